// Round 4
// baseline (1484.305 us; speedup 1.0000x reference)
//
#include <hip/hip_runtime.h>
#include <math.h>

#define N_NODES 50000
#define N_EDGES 800000
#define E_TOT   (N_EDGES + N_NODES)   // edges + self-loops = 850000
#define F_IN    256
#define NHEAD   8
#define CH      32
#define HC      256                   // NHEAD*CH
#define OUT_C   40
#define NEG_SLOPE 0.2f

// ================= GEMM1: h1[N,256] = x[N,256] @ W1[256,256] (fp32)
// 64 rows x 256 cols per block; thread = 4 cols (lane) x 16 rows (wave id).
#define G1_TR 64
#define G1_TK 64
__global__ __launch_bounds__(256) void gemm1_kernel(const float* __restrict__ x,
        const float* __restrict__ W, float* __restrict__ h1) {
    __shared__ float4 xs[G1_TR][G1_TK / 4];    // 64 x 16 float4 = 16 KB
    const int row0 = blockIdx.x * G1_TR;
    const int t    = threadIdx.x;
    const int lane = t & 63;       // col group: cols lane*4 .. lane*4+3
    const int wrow = t >> 6;       // row sub-block: rows wrow*16 .. +15
    const float4* W4 = (const float4*)W;   // W4[k*64 + lane] = W[k][lane*4..+3]

    float4 acc[16];
    #pragma unroll
    for (int i = 0; i < 16; ++i) acc[i] = make_float4(0.f, 0.f, 0.f, 0.f);

    for (int kt = 0; kt < F_IN; kt += G1_TK) {
        __syncthreads();
        // stage x tile: 64 rows x 64 k
        #pragma unroll
        for (int i = t; i < G1_TR * (G1_TK / 4); i += 256) {
            int r  = i >> 4;
            int k4 = i & 15;
            int gr = row0 + r;
            float4 v = make_float4(0.f, 0.f, 0.f, 0.f);
            if (gr < N_NODES) v = ((const float4*)(x + (size_t)gr * F_IN + kt))[k4];
            xs[r][k4] = v;
        }
        __syncthreads();
        #pragma unroll
        for (int k4 = 0; k4 < G1_TK / 4; ++k4) {
            int kbase = kt + k4 * 4;
            float4 w0 = W4[(kbase + 0) * 64 + lane];
            float4 w1 = W4[(kbase + 1) * 64 + lane];
            float4 w2 = W4[(kbase + 2) * 64 + lane];
            float4 w3 = W4[(kbase + 3) * 64 + lane];
            #pragma unroll
            for (int i = 0; i < 16; ++i) {
                float4 xv = xs[wrow * 16 + i][k4];   // wave-uniform -> LDS broadcast
                acc[i].x += xv.x * w0.x + xv.y * w1.x + xv.z * w2.x + xv.w * w3.x;
                acc[i].y += xv.x * w0.y + xv.y * w1.y + xv.z * w2.y + xv.w * w3.y;
                acc[i].z += xv.x * w0.z + xv.y * w1.z + xv.z * w2.z + xv.w * w3.z;
                acc[i].w += xv.x * w0.w + xv.y * w1.w + xv.z * w2.w + xv.w * w3.w;
            }
        }
    }
    #pragma unroll
    for (int i = 0; i < 16; ++i) {
        int gr = row0 + wrow * 16 + i;
        if (gr < N_NODES)
            ((float4*)(h1 + (size_t)gr * HC))[lane] = acc[i];
    }
}

// ================= GEMM2: h2[N,256] = hm[N,32] @ W2[32,256]; W2 in registers
#define G2_ROWS 128
__global__ __launch_bounds__(256) void gemm2_kernel(const float* __restrict__ hm,
        const float* __restrict__ W, float* __restrict__ h2) {
    const int row0 = blockIdx.x * G2_ROWS;
    const int c = threadIdx.x;
    float w[CH];
    #pragma unroll
    for (int k = 0; k < CH; ++k) w[k] = W[k * HC + c];
    for (int i = 0; i < G2_ROWS; ++i) {
        int row = row0 + i;
        if (row >= N_NODES) break;
        const float* hr = hm + (size_t)row * CH;   // block-uniform -> scalar loads
        float a = 0.f;
        #pragma unroll
        for (int k = 0; k < CH; ++k) a += hr[k] * w[k];
        h2[(size_t)row * HC + c] = a;
    }
}

// ================= per-node attention coefficients: asrc/adst [N,8]
__global__ __launch_bounds__(256) void alpha_kernel(const float* __restrict__ h,
        const float* __restrict__ a_src, const float* __restrict__ a_dst,
        float* __restrict__ asrc, float* __restrict__ adst) {
    int t = blockIdx.x * 256 + threadIdx.x;
    if (t >= N_NODES * NHEAD) return;
    int node = t >> 3;
    int hd   = t & 7;
    const float4* hp = (const float4*)(h + (size_t)node * HC + hd * CH);
    const float4* ap = (const float4*)(a_src + hd * CH);
    const float4* dp = (const float4*)(a_dst + hd * CH);
    float s1 = 0.f, s2 = 0.f;
    #pragma unroll
    for (int i = 0; i < CH / 4; ++i) {
        float4 hv = hp[i], av = ap[i], dv = dp[i];
        s1 += hv.x * av.x + hv.y * av.y + hv.z * av.z + hv.w * av.w;
        s2 += hv.x * dv.x + hv.y * dv.y + hv.z * dv.z + hv.w * dv.w;
    }
    asrc[t] = s1;
    adst[t] = s2;
}

// ================= CSR build =================
__global__ __launch_bounds__(256) void deg_kernel(const int* __restrict__ ei,
        int* __restrict__ deg) {
    int j = blockIdx.x * 256 + threadIdx.x;
    if (j >= E_TOT) return;
    int dst = (j < N_EDGES) ? ei[N_EDGES + j] : (j - N_EDGES);
    atomicAdd(&deg[dst], 1);
}

// single-block exclusive scan of deg[50000] -> rowptr[50001]; cursor = copy
__global__ __launch_bounds__(1024) void scan_kernel(const int* __restrict__ deg,
        int* __restrict__ rowptr, int* __restrict__ cursor) {
    __shared__ int part[1024];
    const int t = threadIdx.x;
    const int CHK = (N_NODES + 1023) / 1024;   // 49
    const int base = t * CHK;
    int s = 0;
    for (int i = 0; i < CHK; ++i) {
        int idx = base + i;
        if (idx < N_NODES) s += deg[idx];
    }
    part[t] = s;
    __syncthreads();
    for (int off = 1; off < 1024; off <<= 1) {
        int v = (t >= off) ? part[t - off] : 0;
        __syncthreads();
        part[t] += v;
        __syncthreads();
    }
    int run = (t == 0) ? 0 : part[t - 1];
    for (int i = 0; i < CHK; ++i) {
        int idx = base + i;
        if (idx < N_NODES) {
            rowptr[idx] = run;
            cursor[idx] = run;
            run += deg[idx];
        }
    }
    if (t == 0) rowptr[N_NODES] = E_TOT;
}

__global__ __launch_bounds__(256) void scatter_kernel(const int* __restrict__ ei,
        int* __restrict__ cursor, int* __restrict__ csr_src) {
    int j = blockIdx.x * 256 + threadIdx.x;
    if (j >= E_TOT) return;
    int src, dst;
    if (j < N_EDGES) { src = ei[j]; dst = ei[N_EDGES + j]; }
    else             { src = j - N_EDGES; dst = src; }
    int pos = atomicAdd(&cursor[dst], 1);
    csr_src[pos] = src;
}

// ================= softmax denominators (gather, no atomics)
// thread = (dst, head); writes ew in CSR order and sinv = 1/(8*sum)
__global__ __launch_bounds__(256) void denom_kernel(const int* __restrict__ rowptr,
        const int* __restrict__ csr_src, const float* __restrict__ asrc,
        const float* __restrict__ adst, float* __restrict__ ew,
        float* __restrict__ sinv) {
    int t = blockIdx.x * 256 + threadIdx.x;
    if (t >= N_NODES * NHEAD) return;
    int dst = t >> 3;
    int hd  = t & 7;
    float ad = adst[t];
    int p0 = rowptr[dst], p1 = rowptr[dst + 1];
    float sum = 0.f;
    for (int p = p0; p < p1; ++p) {
        int src = csr_src[p];
        float e = asrc[src * NHEAD + hd] + ad;
        e = e > 0.f ? e : NEG_SLOPE * e;
        float ex = __expf(e);
        ew[(size_t)p * NHEAD + hd] = ex;
        sum += ex;
    }
    sinv[t] = 1.0f / (8.0f * sum);
}

// ================= aggregation (gather, no atomics) + bias + ELU
// thread = (dst, channel)
__global__ __launch_bounds__(256) void aggregate_kernel(const int* __restrict__ rowptr,
        const int* __restrict__ csr_src, const float* __restrict__ ew,
        const float* __restrict__ sinv, const float* __restrict__ h,
        const float* __restrict__ b, float* __restrict__ out) {
    int t = blockIdx.x * 256 + threadIdx.x;
    if (t >= N_NODES * CH) return;
    int dst = t >> 5;
    int c   = t & 31;
    int p0 = rowptr[dst], p1 = rowptr[dst + 1];
    float acc[NHEAD];
    #pragma unroll
    for (int hd = 0; hd < NHEAD; ++hd) acc[hd] = 0.f;
    for (int p = p0; p < p1; ++p) {
        int src = csr_src[p];                       // broadcast across 32 lanes
        const float*  hp = h + (size_t)src * HC + c;
        const float4* wp = (const float4*)(ew + (size_t)p * NHEAD);
        float4 w0 = wp[0], w1 = wp[1];
        acc[0] += w0.x * hp[0 * CH];
        acc[1] += w0.y * hp[1 * CH];
        acc[2] += w0.z * hp[2 * CH];
        acc[3] += w0.w * hp[3 * CH];
        acc[4] += w1.x * hp[4 * CH];
        acc[5] += w1.y * hp[5 * CH];
        acc[6] += w1.z * hp[6 * CH];
        acc[7] += w1.w * hp[7 * CH];
    }
    const float* sp = sinv + (size_t)dst * NHEAD;
    float val = 0.f;
    #pragma unroll
    for (int hd = 0; hd < NHEAD; ++hd) val += sp[hd] * acc[hd];
    val += b[c];
    out[t] = val > 0.f ? val : (__expf(val) - 1.f);
}

// ================= output head: logits = h@Wo + bo, log_softmax (1 wave/node)
__global__ __launch_bounds__(64) void out_kernel(const float* __restrict__ hf,
        const float* __restrict__ Wo, const float* __restrict__ bo,
        float* __restrict__ out) {
    const int n = blockIdx.x;
    const int lane = threadIdx.x;
    __shared__ float hs[CH];
    if (lane < CH) hs[lane] = hf[n * CH + lane];
    __syncthreads();
    float logit = -INFINITY;
    if (lane < OUT_C) {
        float a = bo[lane];
        #pragma unroll
        for (int k = 0; k < CH; ++k) a += hs[k] * Wo[k * OUT_C + lane];
        logit = a;
    }
    float m = logit;
    #pragma unroll
    for (int off = 32; off; off >>= 1) m = fmaxf(m, __shfl_xor(m, off, 64));
    float ex = (lane < OUT_C) ? __expf(logit - m) : 0.f;
    float ssum = ex;
    #pragma unroll
    for (int off = 32; off; off >>= 1) ssum += __shfl_xor(ssum, off, 64);
    if (lane < OUT_C) out[(size_t)n * OUT_C + lane] = logit - m - __logf(ssum);
}

extern "C" void kernel_launch(void* const* d_in, const int* in_sizes, int n_in,
                              void* d_out, int out_size, void* d_ws, size_t ws_size,
                              hipStream_t stream) {
    const float* x      = (const float*)d_in[0];
    const int*   ei     = (const int*)  d_in[1];
    const float* W1     = (const float*)d_in[2];
    const float* a_src1 = (const float*)d_in[3];
    const float* a_dst1 = (const float*)d_in[4];
    const float* b1     = (const float*)d_in[5];
    const float* W2     = (const float*)d_in[6];
    const float* a_src2 = (const float*)d_in[7];
    const float* a_dst2 = (const float*)d_in[8];
    const float* b2     = (const float*)d_in[9];
    const float* Wo     = (const float*)d_in[10];
    const float* bo     = (const float*)d_in[11];
    float* out = (float*)d_out;

    // workspace carve-up (256B-aligned)
    char* ws = (char*)d_ws;
    size_t off = 0;
    auto carve = [&](size_t bytes) { char* p = ws + off; off += (bytes + 255) & ~(size_t)255; return p; };
    float* h_big   = (float*)carve((size_t)N_NODES * HC * 4);      // 51.2 MB
    float* asrc    = (float*)carve((size_t)N_NODES * NHEAD * 4);   // 1.6 MB
    float* adst    = (float*)carve((size_t)N_NODES * NHEAD * 4);
    float* sinv    = (float*)carve((size_t)N_NODES * NHEAD * 4);
    float* ew      = (float*)carve((size_t)E_TOT * NHEAD * 4);     // 27.2 MB
    float* hmid    = (float*)carve((size_t)N_NODES * CH * 4);      // 6.4 MB
    float* hout    = (float*)carve((size_t)N_NODES * CH * 4);      // 6.4 MB
    int*   deg     = (int*)  carve((size_t)N_NODES * 4);
    int*   rowptr  = (int*)  carve((size_t)(N_NODES + 1) * 4);
    int*   cursor  = (int*)  carve((size_t)N_NODES * 4);
    int*   csr_src = (int*)  carve((size_t)E_TOT * 4);             // 3.4 MB

    const int g_gemm1 = (N_NODES + G1_TR - 1) / G1_TR;       // 782
    const int g_gemm2 = (N_NODES + G2_ROWS - 1) / G2_ROWS;   // 391
    const int g_nh    = (N_NODES * NHEAD + 255) / 256;       // 1563
    const int g_edge  = (E_TOT + 255) / 256;                 // 3321
    const int g_aggr  = (N_NODES * CH + 255) / 256;          // 6250

    // ---------- CSR build (shared by both layers) ----------
    hipMemsetAsync(deg, 0, (size_t)N_NODES * 4, stream);
    deg_kernel<<<g_edge, 256, 0, stream>>>(ei, deg);
    scan_kernel<<<1, 1024, 0, stream>>>(deg, rowptr, cursor);
    scatter_kernel<<<g_edge, 256, 0, stream>>>(ei, cursor, csr_src);

    // ---------- layer 1 ----------
    gemm1_kernel<<<g_gemm1, 256, 0, stream>>>(x, W1, h_big);
    alpha_kernel<<<g_nh, 256, 0, stream>>>(h_big, a_src1, a_dst1, asrc, adst);
    denom_kernel<<<g_nh, 256, 0, stream>>>(rowptr, csr_src, asrc, adst, ew, sinv);
    aggregate_kernel<<<g_aggr, 256, 0, stream>>>(rowptr, csr_src, ew, sinv, h_big, b1, hmid);

    // ---------- layer 2 ----------
    gemm2_kernel<<<g_gemm2, 256, 0, stream>>>(hmid, W2, h_big);
    alpha_kernel<<<g_nh, 256, 0, stream>>>(h_big, a_src2, a_dst2, asrc, adst);
    denom_kernel<<<g_nh, 256, 0, stream>>>(rowptr, csr_src, asrc, adst, ew, sinv);
    aggregate_kernel<<<g_aggr, 256, 0, stream>>>(rowptr, csr_src, ew, sinv, h_big, b2, hout);

    // ---------- output head ----------
    out_kernel<<<N_NODES, 64, 0, stream>>>(hout, Wo, bo, out);
}